// Round 1
// baseline (1250.505 us; speedup 1.0000x reference)
//
#include <hip/hip_runtime.h>

namespace {
constexpr int UNITS = 2048;
constexpr int D_IN  = 96;
constexpr int BATCH = 64;
constexpr int T     = 512;
constexpr int NNZ   = 960;   // D_IN * C_IN
constexpr int C_REC = 10;
constexpr int CHUNK = 128;   // x timesteps staged in LDS per refill
constexpr int NT    = 1024;  // threads per block; one block per batch element

// LDS byte-offset arena
constexpr int HA = 0;          // h ping   (2048 f32 = 8 KB)
constexpr int HB = 8192;       // h pong   (8 KB)
constexpr int IA = 16384;      // input_part ping (8 KB)
constexpr int IB = 24576;      // input_part pong (8 KB)
constexpr int XO = 32768;      // x chunk  (128*96 f32 = 48 KB)
constexpr int LDS_BYTES = XO + CHUNK * D_IN * 4;   // 80 KB total
}

// Barrier WITHOUT vmcnt drain: __syncthreads() emits s_waitcnt vmcnt(0) which
// would stall every step on the streaming out-stores. We only need LDS
// visibility -> lgkmcnt(0) + s_barrier.
__device__ __forceinline__ void bar_lds() {
  asm volatile("s_waitcnt lgkmcnt(0)\n\ts_barrier" ::: "memory");
}

// tanh(x) = 1 - 2/(exp(2x)+1); exact at +-inf, abs err ~1e-7 vs 2e-2 threshold
__device__ __forceinline__ float fast_tanh(float x) {
  float e = __expf(2.0f * x);
  return 1.0f - __fdividef(2.0f, e + 1.0f);
}

// One timestep. HC = h current, HN = h next, IR = input_part consumed this
// step (read then re-zeroed), IW = input_part being built for step t+1.
// Hazards: everything cross-thread is separated by exactly one bar_lds per
// phase; scatter(t+1)->IW runs concurrently with gather(t)<-IR (disjoint).
template <int HC, int HN, int IR, int IW>
__device__ __forceinline__ void step_phase(
    char* smem, int tid, int slot_next, bool do_scatter,
    int krb, int kcb, float kv,
    const int* idxb0, const int* idxb1, const float* w0, const float* w1,
    float2 bias2, float2* outp, int t)
{
  if (do_scatter && tid < NNZ) {
    float xv = *(const float*)(smem + XO + slot_next * (D_IN * 4) + krb);
    atomicAdd((float*)(smem + IW + kcb), xv * kv);   // ds_add_f32, no return
  }
  // consume input_part for this step, then re-zero for the scatter 2 steps out
  float2 in2 = *(float2*)(smem + IR + tid * 8);
  *(float2*)(smem + IR + tid * 8) = make_float2(0.f, 0.f);
  float s0 = in2.x + bias2.x;
  float s1 = in2.y + bias2.y;
#pragma unroll
  for (int c = 0; c < C_REC; ++c) {   // 20 random ds_read_b32 — the hot pipe
    s0 += *(const float*)(smem + HC + idxb0[c]) * w0[c];
    s1 += *(const float*)(smem + HC + idxb1[c]) * w1[c];
  }
  float2 hh = make_float2(fast_tanh(s0), fast_tanh(s1));
  *(float2*)(smem + HN + tid * 8) = hh;      // publish h_{t+1}
  outp[(size_t)t * (UNITS / 2)] = hh;        // streaming store, never waited on
  bar_lds();
}

__global__ __launch_bounds__(NT) void reservoir_kernel(
    const float* __restrict__ inputs, const float* __restrict__ state0,
    const float* __restrict__ kvals,  const float* __restrict__ rvals,
    const float* __restrict__ bias,   const int* __restrict__ krows,
    const int* __restrict__ kcols,    const int* __restrict__ ridx,
    float* __restrict__ out)
{
  __shared__ __align__(16) char smem[LDS_BYTES];
  const int tid = threadIdx.x;
  const int b   = blockIdx.x;
  const int u0  = tid * 2;          // each thread owns units u0, u0+1

  // zero input_part ping+pong (16 KB): one float4 store per thread
  *(float4*)(smem + IA + tid * 16) = make_float4(0.f, 0.f, 0.f, 0.f);
  // stage h_0
  *(float2*)(smem + HA + tid * 8) = *(const float2*)(state0 + b * UNITS + u0);

  // hoist recurrent weights into VGPRs: 20 byte-offsets + 20 vals per thread
  int   idxb0[C_REC], idxb1[C_REC];
  float w0[C_REC], w1[C_REC];
#pragma unroll
  for (int c = 0; c < C_REC; ++c) {
    idxb0[c] = ridx[u0 * C_REC + c] * 4;
    idxb1[c] = ridx[u0 * C_REC + C_REC + c] * 4;
    w0[c]    = rvals[u0 * C_REC + c];
    w1[c]    = rvals[u0 * C_REC + C_REC + c];
  }
  const float2 bias2 = *(const float2*)(bias + u0);

  // input-kernel COO entry for this thread (960 entries, threads 960..1023 idle)
  int krb = 0, kcb = 0; float kv = 0.f;
  if (tid < NNZ) {
    krb = krows[tid] * 4;
    kcb = kcols[tid] * 4;
    kv  = kvals[tid];
  }

  const float* xin  = inputs + (size_t)b * (T * D_IN);
  float2*      outp = (float2*)out + (size_t)b * (T * (UNITS / 2)) + tid;

  __syncthreads();   // prologue: full barrier once is fine

  for (int tb = 0; tb < T; tb += CHUNK) {
    // bulk-refill x chunk (48 KB); all readers of the previous chunk are at
    // least one phase-barrier behind us
#pragma unroll
    for (int k = 0; k < 3; ++k) {
      float4 v = *(const float4*)(xin + tb * D_IN + (tid + k * NT) * 4);
      *(float4*)(smem + XO + (tid + k * NT) * 16) = v;
    }
    bar_lds();
    // prime input_part for the first step of this chunk (slot 0 -> ping buf;
    // ping was left zeroed by the previous chunk's last even phase / prologue)
    if (tid < NNZ) {
      float xv = *(const float*)(smem + XO + krb);
      atomicAdd((float*)(smem + IA + kcb), xv * kv);
    }
    bar_lds();
#pragma unroll 1
    for (int ts = 0; ts < CHUNK; ts += 2) {
      step_phase<HA, HB, IA, IB>(smem, tid, ts + 1, true,
                                 krb, kcb, kv, idxb0, idxb1, w0, w1,
                                 bias2, outp, tb + ts);
      step_phase<HB, HA, IB, IA>(smem, tid, ts + 2, (ts + 2) < CHUNK,
                                 krb, kcb, kv, idxb0, idxb1, w0, w1,
                                 bias2, outp, tb + ts + 1);
    }
  }
}

extern "C" void kernel_launch(void* const* d_in, const int* in_sizes, int n_in,
                              void* d_out, int out_size, void* d_ws, size_t ws_size,
                              hipStream_t stream) {
  const float* inputs = (const float*)d_in[0];
  const float* state0 = (const float*)d_in[1];
  const float* kvals  = (const float*)d_in[2];
  const float* rvals  = (const float*)d_in[3];
  const float* bias   = (const float*)d_in[4];
  const int*   krows  = (const int*)d_in[5];
  const int*   kcols  = (const int*)d_in[6];
  const int*   ridx   = (const int*)d_in[7];

  reservoir_kernel<<<dim3(BATCH), dim3(NT), 0, stream>>>(
      inputs, state0, kvals, rvals, bias, krows, kcols, ridx, (float*)d_out);
}